// Round 1
// baseline (162.430 us; speedup 1.0000x reference)
//
#include <hip/hip_runtime.h>
#include <hip/hip_bf16.h>

#define DD 32
#define P_MAX 118
#define N_MAX 236
#define TBL (P_MAX * N_MAX)

// ---------------------------------------------------------------------------
// Kernel 1: the two sequential SiLU-matvec chains.
// grid = 2 blocks (block 0: proton chain, block 1: neutron chain), 64 threads.
// Lane layout: ch = lane & 31; lanes 32..63 shadow lanes 0..31 (same compute),
// so v_readlane from lanes 0..31 serves the whole wave. Critical path is
// VALU-only: exp/rcp for silu, readlane broadcast, fmac dot. No DS ops.
// ---------------------------------------------------------------------------
__global__ __launch_bounds__(64) void chain_kernel(
    const float* __restrict__ emb,
    const float* __restrict__ Wp, const float* __restrict__ bp,
    const float* __restrict__ Wn, const float* __restrict__ bn,
    float* __restrict__ ws)
{
    const int lane = threadIdx.x;
    const int ch = lane & 31;

    const float* W;
    const float* b;
    const float* e0;
    float* out;
    int len;
    if (blockIdx.x == 0) {
        W = Wp; b = bp; e0 = emb;       out = ws;              len = P_MAX;
    } else {
        W = Wn; b = bn; e0 = emb + DD;  out = ws + P_MAX * DD; len = N_MAX;
    }

    // lane ch holds weight row W[ch][0..31]
    float w[32];
#pragma unroll
    for (int q = 0; q < 8; ++q) {
        float4 v = reinterpret_cast<const float4*>(W + ch * 32)[q];
        w[4 * q + 0] = v.x; w[4 * q + 1] = v.y;
        w[4 * q + 2] = v.z; w[4 * q + 3] = v.w;
    }
    const float bias = b[ch];
    float p = e0[ch];

    for (int t = 0; t < len; ++t) {
        // s = silu(p) = p / (1 + exp(-p))
        float e = __expf(-p);
        float s = p * __builtin_amdgcn_rcpf(1.0f + e);
        int sb = __float_as_int(s);

        float a0 = 0.0f, a1 = 0.0f, a2 = 0.0f, a3 = 0.0f;
#pragma unroll
        for (int k = 0; k < 32; k += 4) {
            a0 += __int_as_float(__builtin_amdgcn_readlane(sb, k + 0)) * w[k + 0];
            a1 += __int_as_float(__builtin_amdgcn_readlane(sb, k + 1)) * w[k + 1];
            a2 += __int_as_float(__builtin_amdgcn_readlane(sb, k + 2)) * w[k + 2];
            a3 += __int_as_float(__builtin_amdgcn_readlane(sb, k + 3)) * w[k + 3];
        }
        p = bias + ((a0 + a1) + (a2 + a3));
        if (lane < 32) out[t * DD + ch] = p;   // store is off the critical path
    }
}

// ---------------------------------------------------------------------------
// Kernel 2: build the 118x236 output table. One thread per (p_idx, n_idx).
// Weights are wave-uniform -> compiler emits scalar (s_load) accesses.
// ---------------------------------------------------------------------------
__global__ __launch_bounds__(256) void table_kernel(
    const float* __restrict__ ws,
    const float* __restrict__ W1, const float* __restrict__ b1,
    const float* __restrict__ ln_g, const float* __restrict__ ln_b,
    const float* __restrict__ W2, const float* __restrict__ b2,
    const float* __restrict__ Wr, const float* __restrict__ br,
    float2* __restrict__ table)
{
    const int e = blockIdx.x * 256 + threadIdx.x;
    if (e >= TBL) return;
    const int pi = e / N_MAX;
    const int ni = e - pi * N_MAX;

    const float* pf = ws + pi * DD;
    const float* nf = ws + P_MAX * DD + ni * DD;

    float hc[64];
#pragma unroll
    for (int q = 0; q < 8; ++q) {
        float4 v = reinterpret_cast<const float4*>(pf)[q];
        hc[4 * q + 0] = v.x; hc[4 * q + 1] = v.y;
        hc[4 * q + 2] = v.z; hc[4 * q + 3] = v.w;
    }
#pragma unroll
    for (int q = 0; q < 8; ++q) {
        float4 v = reinterpret_cast<const float4*>(nf)[q];
        hc[32 + 4 * q + 0] = v.x; hc[32 + 4 * q + 1] = v.y;
        hc[32 + 4 * q + 2] = v.z; hc[32 + 4 * q + 3] = v.w;
    }

    // h = silu(hc @ W1^T + b1)
    float h[32];
#pragma unroll
    for (int j = 0; j < 32; ++j) {
        float a = b1[j];
#pragma unroll
        for (int k = 0; k < 64; ++k) a += hc[k] * W1[j * 64 + k];
        float ee = __expf(-a);
        h[j] = a * __builtin_amdgcn_rcpf(1.0f + ee);
    }

    // layernorm
    float mu = 0.0f;
#pragma unroll
    for (int j = 0; j < 32; ++j) mu += h[j];
    mu *= (1.0f / 32.0f);
    float var = 0.0f;
#pragma unroll
    for (int j = 0; j < 32; ++j) {
        float d = h[j] - mu;
        var += d * d;
    }
    var *= (1.0f / 32.0f);
    const float inv = __builtin_amdgcn_rsqf(var + 1e-5f);
#pragma unroll
    for (int j = 0; j < 32; ++j)
        h[j] = (h[j] - mu) * inv * ln_g[j] + ln_b[j];

    // h2 = h @ W2^T + b2
    float h2[32];
#pragma unroll
    for (int j = 0; j < 32; ++j) {
        float a = b2[j];
#pragma unroll
        for (int k = 0; k < 32; ++k) a += h[k] * W2[j * 32 + k];
        h2[j] = a;
    }

    // out = h2 @ Wr^T + br  (OUT = 2)
    float o0 = br[0], o1 = br[1];
#pragma unroll
    for (int k = 0; k < 32; ++k) {
        o0 += h2[k] * Wr[k];
        o1 += h2[k] * Wr[32 + k];
    }
    table[e] = make_float2(o0, o1);
}

// ---------------------------------------------------------------------------
// Kernel 3: per-sample gather. Coalesced 8B in, 8B out; random 8B table read
// (223 KB table -> L2-resident).
// ---------------------------------------------------------------------------
__global__ __launch_bounds__(256) void gather_kernel(
    const int2* __restrict__ x,
    const float2* __restrict__ table,
    float2* __restrict__ out,
    int B)
{
    const int i = blockIdx.x * 256 + threadIdx.x;
    if (i >= B) return;
    int2 v = x[i];
    out[i] = table[(v.x - 1) * N_MAX + (v.y - 1)];
}

extern "C" void kernel_launch(void* const* d_in, const int* in_sizes, int n_in,
                              void* d_out, int out_size, void* d_ws, size_t ws_size,
                              hipStream_t stream) {
    const int*   x    = (const int*)d_in[0];
    const float* emb  = (const float*)d_in[1];
    const float* Wp   = (const float*)d_in[2];
    const float* bp   = (const float*)d_in[3];
    const float* Wn   = (const float*)d_in[4];
    const float* bn   = (const float*)d_in[5];
    const float* W1   = (const float*)d_in[6];
    const float* b1   = (const float*)d_in[7];
    const float* ln_g = (const float*)d_in[8];
    const float* ln_b = (const float*)d_in[9];
    const float* W2   = (const float*)d_in[10];
    const float* b2   = (const float*)d_in[11];
    const float* Wr   = (const float*)d_in[12];
    const float* br   = (const float*)d_in[13];

    const int B = in_sizes[0] / 2;

    float* wsf = (float*)d_ws;
    // ws layout (floats): [0, 118*32) pstates | [118*32, 354*32) nstates | table
    float2* table = (float2*)(wsf + (P_MAX + N_MAX) * DD);

    chain_kernel<<<2, 64, 0, stream>>>(emb, Wp, bp, Wn, bn, wsf);

    table_kernel<<<(TBL + 255) / 256, 256, 0, stream>>>(
        wsf, W1, b1, ln_g, ln_b, W2, b2, Wr, br, table);

    gather_kernel<<<(B + 255) / 256, 256, 0, stream>>>(
        (const int2*)x, table, (float2*)d_out, B);
}

// Round 2
// 152.282 us; speedup vs baseline: 1.0666x; 1.0666x over previous
//
#include <hip/hip_runtime.h>
#include <hip/hip_bf16.h>

#define DD 32
#define P_MAX 118
#define N_MAX 236
#define TBL (P_MAX * N_MAX)

// ---------------------------------------------------------------------------
// Kernel 1: the two sequential SiLU-matvec chains.
// grid = 2 blocks (block 0: proton chain, block 1: neutron chain), 64 threads.
// Lane layout: ch = lane & 31; lanes 32..63 shadow lanes 0..31, so
// v_readlane from lanes 0..31 serves the whole wave. Critical path is
// VALU-only: exp/rcp for silu, readlane broadcast, fmac dot. No DS ops.
// ---------------------------------------------------------------------------
__global__ __launch_bounds__(64) void chain_kernel(
    const float* __restrict__ emb,
    const float* __restrict__ Wp, const float* __restrict__ bp,
    const float* __restrict__ Wn, const float* __restrict__ bn,
    float* __restrict__ ws)
{
    const int lane = threadIdx.x;
    const int ch = lane & 31;

    const float* W;
    const float* b;
    const float* e0;
    float* out;
    int len;
    if (blockIdx.x == 0) {
        W = Wp; b = bp; e0 = emb;       out = ws;              len = P_MAX;
    } else {
        W = Wn; b = bn; e0 = emb + DD;  out = ws + P_MAX * DD; len = N_MAX;
    }

    // lane ch holds weight row W[ch][0..31]
    float w[32];
#pragma unroll
    for (int q = 0; q < 8; ++q) {
        float4 v = reinterpret_cast<const float4*>(W + ch * 32)[q];
        w[4 * q + 0] = v.x; w[4 * q + 1] = v.y;
        w[4 * q + 2] = v.z; w[4 * q + 3] = v.w;
    }
    const float bias = b[ch];
    float p = e0[ch];

    for (int t = 0; t < len; ++t) {
        // s = silu(p) = p / (1 + exp(-p))
        float e = __expf(-p);
        float s = p * __builtin_amdgcn_rcpf(1.0f + e);
        int sb = __float_as_int(s);

        float a0 = 0.0f, a1 = 0.0f, a2 = 0.0f, a3 = 0.0f;
#pragma unroll
        for (int k = 0; k < 32; k += 4) {
            a0 += __int_as_float(__builtin_amdgcn_readlane(sb, k + 0)) * w[k + 0];
            a1 += __int_as_float(__builtin_amdgcn_readlane(sb, k + 1)) * w[k + 1];
            a2 += __int_as_float(__builtin_amdgcn_readlane(sb, k + 2)) * w[k + 2];
            a3 += __int_as_float(__builtin_amdgcn_readlane(sb, k + 3)) * w[k + 3];
        }
        p = bias + ((a0 + a1) + (a2 + a3));
        if (lane < 32) out[t * DD + ch] = p;   // store is off the critical path
    }
}

// ---------------------------------------------------------------------------
// Kernel 2: build the 118x236 output table. One thread per (p_idx, n_idx).
// 64-thread blocks -> 436 blocks -> all 256 CUs busy (vs 109 with 256-blocks).
// __launch_bounds__(64,1): let the allocator use plenty of VGPRs so pf/nf/h
// stay in registers (R1's 60-VGPR version spilled hc[64] to scratch -> 43us).
// Weights are wave-uniform -> s_load / SGPR operands.
// ---------------------------------------------------------------------------
__global__ __launch_bounds__(64, 1) void table_kernel(
    const float* __restrict__ ws,
    const float* __restrict__ W1, const float* __restrict__ b1,
    const float* __restrict__ ln_g, const float* __restrict__ ln_b,
    const float* __restrict__ W2, const float* __restrict__ b2,
    const float* __restrict__ Wr, const float* __restrict__ br,
    float2* __restrict__ table)
{
    const int e = blockIdx.x * 64 + threadIdx.x;
    if (e >= TBL) return;
    const int pi = e / N_MAX;
    const int ni = e - pi * N_MAX;

    const float4* pf4 = reinterpret_cast<const float4*>(ws + pi * DD);
    const float4* nf4 = reinterpret_cast<const float4*>(ws + P_MAX * DD + ni * DD);

    float4 pc[8], nc[8];
#pragma unroll
    for (int q = 0; q < 8; ++q) pc[q] = pf4[q];
#pragma unroll
    for (int q = 0; q < 8; ++q) nc[q] = nf4[q];

    // ---- layer 1: h = silu(hc @ W1^T + b1), hc = [pf | nf] (64 wide) ----
    float h[32];
#pragma unroll
    for (int j0 = 0; j0 < 32; j0 += 8) {
        float acc[8];
#pragma unroll
        for (int u = 0; u < 8; ++u) acc[u] = b1[j0 + u];
#pragma unroll
        for (int q = 0; q < 8; ++q) {        // proton half: k = 4q..4q+3
            float4 c = pc[q];
#pragma unroll
            for (int u = 0; u < 8; ++u) {
                const float* wr = W1 + (j0 + u) * 64 + 4 * q;
                acc[u] = fmaf(c.x, wr[0], acc[u]);
                acc[u] = fmaf(c.y, wr[1], acc[u]);
                acc[u] = fmaf(c.z, wr[2], acc[u]);
                acc[u] = fmaf(c.w, wr[3], acc[u]);
            }
        }
#pragma unroll
        for (int q = 0; q < 8; ++q) {        // neutron half: k = 32+4q..
            float4 c = nc[q];
#pragma unroll
            for (int u = 0; u < 8; ++u) {
                const float* wr = W1 + (j0 + u) * 64 + 32 + 4 * q;
                acc[u] = fmaf(c.x, wr[0], acc[u]);
                acc[u] = fmaf(c.y, wr[1], acc[u]);
                acc[u] = fmaf(c.z, wr[2], acc[u]);
                acc[u] = fmaf(c.w, wr[3], acc[u]);
            }
        }
#pragma unroll
        for (int u = 0; u < 8; ++u) {
            float a = acc[u];
            float ee = __expf(-a);
            h[j0 + u] = a * __builtin_amdgcn_rcpf(1.0f + ee);
        }
    }

    // ---- layernorm ----
    float mu = 0.0f;
#pragma unroll
    for (int j = 0; j < 32; ++j) mu += h[j];
    mu *= (1.0f / 32.0f);
    float var = 0.0f;
#pragma unroll
    for (int j = 0; j < 32; ++j) {
        float d = h[j] - mu;
        var = fmaf(d, d, var);
    }
    var *= (1.0f / 32.0f);
    const float inv = __builtin_amdgcn_rsqf(var + 1e-5f);
#pragma unroll
    for (int j = 0; j < 32; ++j)
        h[j] = (h[j] - mu) * inv * ln_g[j] + ln_b[j];

    // ---- layer 2: h2 = h @ W2^T + b2 ----
    float h2[32];
#pragma unroll
    for (int j0 = 0; j0 < 32; j0 += 8) {
        float acc[8];
#pragma unroll
        for (int u = 0; u < 8; ++u) acc[u] = b2[j0 + u];
#pragma unroll
        for (int k = 0; k < 32; ++k) {
#pragma unroll
            for (int u = 0; u < 8; ++u)
                acc[u] = fmaf(h[k], W2[(j0 + u) * 32 + k], acc[u]);
        }
#pragma unroll
        for (int u = 0; u < 8; ++u) h2[j0 + u] = acc[u];
    }

    // ---- readout: out = h2 @ Wr^T + br (OUT = 2) ----
    float o0 = br[0], o1 = br[1];
    float p0 = 0.0f, p1 = 0.0f, q0 = 0.0f, q1 = 0.0f;
#pragma unroll
    for (int k = 0; k < 32; k += 2) {
        o0 = fmaf(h2[k], Wr[k], o0);
        p0 = fmaf(h2[k + 1], Wr[k + 1], p0);
        o1 = fmaf(h2[k], Wr[32 + k], o1);
        p1 = fmaf(h2[k + 1], Wr[32 + k + 1], p1);
    }
    q0 = o0 + p0; q1 = o1 + p1;
    table[e] = make_float2(q0, q1);
}

// ---------------------------------------------------------------------------
// Kernel 3: per-sample gather, 2 samples per thread (16B in / 16B out).
// Table (223 KB) is L2-resident; x-read and out-write fully coalesced.
// ---------------------------------------------------------------------------
__global__ __launch_bounds__(256) void gather_kernel(
    const int4* __restrict__ x2,
    const float2* __restrict__ table,
    float4* __restrict__ out2,
    int B2)
{
    const int i = blockIdx.x * 256 + threadIdx.x;
    if (i >= B2) return;
    int4 v = x2[i];
    float2 a = table[(v.x - 1) * N_MAX + (v.y - 1)];
    float2 b = table[(v.z - 1) * N_MAX + (v.w - 1)];
    out2[i] = make_float4(a.x, a.y, b.x, b.y);
}

extern "C" void kernel_launch(void* const* d_in, const int* in_sizes, int n_in,
                              void* d_out, int out_size, void* d_ws, size_t ws_size,
                              hipStream_t stream) {
    const int*   x    = (const int*)d_in[0];
    const float* emb  = (const float*)d_in[1];
    const float* Wp   = (const float*)d_in[2];
    const float* bp   = (const float*)d_in[3];
    const float* Wn   = (const float*)d_in[4];
    const float* bn   = (const float*)d_in[5];
    const float* W1   = (const float*)d_in[6];
    const float* b1   = (const float*)d_in[7];
    const float* ln_g = (const float*)d_in[8];
    const float* ln_b = (const float*)d_in[9];
    const float* W2   = (const float*)d_in[10];
    const float* b2   = (const float*)d_in[11];
    const float* Wr   = (const float*)d_in[12];
    const float* br   = (const float*)d_in[13];

    const int B = in_sizes[0] / 2;

    float* wsf = (float*)d_ws;
    // ws layout (floats): [0, 118*32) pstates | [118*32, 354*32) nstates | table
    float2* table = (float2*)(wsf + (P_MAX + N_MAX) * DD);

    chain_kernel<<<2, 64, 0, stream>>>(emb, Wp, bp, Wn, bn, wsf);

    table_kernel<<<(TBL + 63) / 64, 64, 0, stream>>>(
        wsf, W1, b1, ln_g, ln_b, W2, b2, Wr, br, table);

    gather_kernel<<<(B / 2 + 255) / 256, 256, 0, stream>>>(
        (const int4*)x, table, (float4*)d_out, B / 2);
}

// Round 4
// 139.886 us; speedup vs baseline: 1.1612x; 1.0886x over previous
//
#include <hip/hip_runtime.h>
#include <hip/hip_bf16.h>

#define DD 32
#define P_MAX 118
#define N_MAX 236
#define TBL (P_MAX * N_MAX)

// native clang vector types for nontemporal builtins (HIP_vector_type invalid)
typedef int   ivec4 __attribute__((ext_vector_type(4)));
typedef float fvec4 __attribute__((ext_vector_type(4)));

// ws float offsets
#define PST 0                       // proton states  118*32
#define NST (P_MAX * DD)            // neutron states 236*32 at 3776
#define UOF ((P_MAX + N_MAX) * DD)  // U_T 32x118 at 11328
#define VOF (UOF + DD * P_MAX)      // V_T 32x236 at 15104
#define TOF (VOF + DD * N_MAX)      // table (float2) at 22656 floats

// ---------------------------------------------------------------------------
// Kernel 1 (unchanged control): two sequential SiLU-matvec chains.
// grid = 2 blocks x 64. Critical path is VALU-only readlane broadcast + fmac.
// ---------------------------------------------------------------------------
__global__ __launch_bounds__(64) void chain_kernel(
    const float* __restrict__ emb,
    const float* __restrict__ Wp, const float* __restrict__ bp,
    const float* __restrict__ Wn, const float* __restrict__ bn,
    float* __restrict__ ws)
{
    const int lane = threadIdx.x;
    const int ch = lane & 31;

    const float* W;
    const float* b;
    const float* e0;
    float* out;
    int len;
    if (blockIdx.x == 0) {
        W = Wp; b = bp; e0 = emb;       out = ws + PST; len = P_MAX;
    } else {
        W = Wn; b = bn; e0 = emb + DD;  out = ws + NST; len = N_MAX;
    }

    float w[32];
#pragma unroll
    for (int q = 0; q < 8; ++q) {
        float4 v = reinterpret_cast<const float4*>(W + ch * 32)[q];
        w[4 * q + 0] = v.x; w[4 * q + 1] = v.y;
        w[4 * q + 2] = v.z; w[4 * q + 3] = v.w;
    }
    const float bias = b[ch];
    float p = e0[ch];

    for (int t = 0; t < len; ++t) {
        float e = __expf(-p);
        float s = p * __builtin_amdgcn_rcpf(1.0f + e);
        int sb = __float_as_int(s);

        float a0 = 0.0f, a1 = 0.0f, a2 = 0.0f, a3 = 0.0f;
#pragma unroll
        for (int k = 0; k < 32; k += 4) {
            a0 += __int_as_float(__builtin_amdgcn_readlane(sb, k + 0)) * w[k + 0];
            a1 += __int_as_float(__builtin_amdgcn_readlane(sb, k + 1)) * w[k + 1];
            a2 += __int_as_float(__builtin_amdgcn_readlane(sb, k + 2)) * w[k + 2];
            a3 += __int_as_float(__builtin_amdgcn_readlane(sb, k + 3)) * w[k + 3];
        }
        p = bias + ((a0 + a1) + (a2 + a3));
        if (lane < 32) out[t * DD + ch] = p;
    }
}

// ---------------------------------------------------------------------------
// Kernel 2: layer-1 is separable. Precompute
//   U_T[j][t]  = sum_k pstate[t][k] * W1[j][k]            (32 x 118)
//   V_T[j][t]  = b1[j] + sum_k nstate[t][k] * W1[j][32+k] (32 x 236)
// grid = (6, 32): x<2 proton, x>=2 neutron; y = output channel j.
// Transposed layout -> table_kernel's V reads are lane-coalesced.
// ---------------------------------------------------------------------------
__global__ __launch_bounds__(64) void uv_kernel(
    const float* __restrict__ ws_in,
    const float* __restrict__ W1, const float* __restrict__ b1,
    float* __restrict__ ws_out)
{
    const int j = blockIdx.y;
    const int bx = blockIdx.x;
    const int lane = threadIdx.x;
    const bool prot = bx < 2;
    const int t = prot ? bx * 64 + lane : (bx - 2) * 64 + lane;
    const int len = prot ? P_MAX : N_MAX;
    if (t >= len) return;

    const float* st = ws_in + (prot ? PST : NST) + t * DD;
    const float* wr = W1 + j * 64 + (prot ? 0 : 32);
    float acc = prot ? 0.0f : b1[j];
#pragma unroll
    for (int q = 0; q < 8; ++q) {
        float4 s4 = reinterpret_cast<const float4*>(st)[q];
        acc = fmaf(s4.x, wr[4 * q + 0], acc);
        acc = fmaf(s4.y, wr[4 * q + 1], acc);
        acc = fmaf(s4.z, wr[4 * q + 2], acc);
        acc = fmaf(s4.w, wr[4 * q + 3], acc);
    }
    if (prot) ws_out[UOF + j * P_MAX + t] = acc;
    else      ws_out[VOF + j * N_MAX + t] = acc;
}

// ---------------------------------------------------------------------------
// Kernel 3: build the table. Per thread:
//   h = silu(U_T[:,pi] + V_T[:,ni]); layernorm; W2 matvec; Wr readout.
// ~1500 VALU ops/thread vs R2's ~3300. U reads broadcast, V reads coalesced.
// ---------------------------------------------------------------------------
__global__ __launch_bounds__(64, 1) void table_kernel(
    const float* __restrict__ ws,
    const float* __restrict__ ln_g, const float* __restrict__ ln_b,
    const float* __restrict__ W2, const float* __restrict__ b2,
    const float* __restrict__ Wr, const float* __restrict__ br,
    float2* __restrict__ table)
{
    const int e = blockIdx.x * 64 + threadIdx.x;
    if (e >= TBL) return;
    const int pi = e / N_MAX;
    const int ni = e - pi * N_MAX;

    const float* UT = ws + UOF;   // 32 x 118
    const float* VT = ws + VOF;   // 32 x 236

    float h[32];
    float mu = 0.0f;
#pragma unroll
    for (int j = 0; j < 32; ++j) {
        float a = UT[j * P_MAX + pi] + VT[j * N_MAX + ni];
        float ee = __expf(-a);
        float s = a * __builtin_amdgcn_rcpf(1.0f + ee);
        h[j] = s;
        mu += s;
    }
    mu *= (1.0f / 32.0f);
    float var = 0.0f;
#pragma unroll
    for (int j = 0; j < 32; ++j) {
        float d = h[j] - mu;
        var = fmaf(d, d, var);
    }
    var *= (1.0f / 32.0f);
    const float inv = __builtin_amdgcn_rsqf(var + 1e-5f);
#pragma unroll
    for (int j = 0; j < 32; ++j)
        h[j] = (h[j] - mu) * inv * ln_g[j] + ln_b[j];

    // h2 = h @ W2^T + b2
    float h2[32];
#pragma unroll
    for (int j0 = 0; j0 < 32; j0 += 8) {
        float acc[8];
#pragma unroll
        for (int u = 0; u < 8; ++u) acc[u] = b2[j0 + u];
#pragma unroll
        for (int k = 0; k < 32; ++k) {
#pragma unroll
            for (int u = 0; u < 8; ++u)
                acc[u] = fmaf(h[k], W2[(j0 + u) * 32 + k], acc[u]);
        }
#pragma unroll
        for (int u = 0; u < 8; ++u) h2[j0 + u] = acc[u];
    }

    float o0 = br[0], o1 = br[1];
    float p0 = 0.0f, p1 = 0.0f;
#pragma unroll
    for (int k = 0; k < 32; k += 2) {
        o0 = fmaf(h2[k], Wr[k], o0);
        p0 = fmaf(h2[k + 1], Wr[k + 1], p0);
        o1 = fmaf(h2[k], Wr[32 + k], o1);
        p1 = fmaf(h2[k + 1], Wr[32 + k + 1], p1);
    }
    table[e] = make_float2(o0 + p0, o1 + p1);
}

// ---------------------------------------------------------------------------
// Kernel 4: gather, 4 samples/thread. Nontemporal on the x-stream and the
// out-stream (read/write-once, 8 MB each) so the L2 stays dedicated to the
// 223 KB table. Uses native clang vectors for the nontemporal builtins.
// ---------------------------------------------------------------------------
__global__ __launch_bounds__(256) void gather_kernel(
    const ivec4* __restrict__ x4,
    const float2* __restrict__ table,
    fvec4* __restrict__ out4,
    int B4)
{
    const int i = blockIdx.x * 256 + threadIdx.x;
    if (i >= B4) return;
    ivec4 a = __builtin_nontemporal_load(x4 + 2 * i);
    ivec4 b = __builtin_nontemporal_load(x4 + 2 * i + 1);
    float2 t0 = table[(a.x - 1) * N_MAX + (a.y - 1)];
    float2 t1 = table[(a.z - 1) * N_MAX + (a.w - 1)];
    float2 t2 = table[(b.x - 1) * N_MAX + (b.y - 1)];
    float2 t3 = table[(b.z - 1) * N_MAX + (b.w - 1)];
    fvec4 o0v = {t0.x, t0.y, t1.x, t1.y};
    fvec4 o1v = {t2.x, t2.y, t3.x, t3.y};
    __builtin_nontemporal_store(o0v, out4 + 2 * i);
    __builtin_nontemporal_store(o1v, out4 + 2 * i + 1);
}

extern "C" void kernel_launch(void* const* d_in, const int* in_sizes, int n_in,
                              void* d_out, int out_size, void* d_ws, size_t ws_size,
                              hipStream_t stream) {
    const int*   x    = (const int*)d_in[0];
    const float* emb  = (const float*)d_in[1];
    const float* Wp   = (const float*)d_in[2];
    const float* bp   = (const float*)d_in[3];
    const float* Wn   = (const float*)d_in[4];
    const float* bn   = (const float*)d_in[5];
    const float* W1   = (const float*)d_in[6];
    const float* b1   = (const float*)d_in[7];
    const float* ln_g = (const float*)d_in[8];
    const float* ln_b = (const float*)d_in[9];
    const float* W2   = (const float*)d_in[10];
    const float* b2   = (const float*)d_in[11];
    const float* Wr   = (const float*)d_in[12];
    const float* br   = (const float*)d_in[13];

    const int B = in_sizes[0] / 2;

    float* wsf = (float*)d_ws;
    float2* table = (float2*)(wsf + TOF);

    chain_kernel<<<2, 64, 0, stream>>>(emb, Wp, bp, Wn, bn, wsf);

    uv_kernel<<<dim3(6, 32), 64, 0, stream>>>(wsf, W1, b1, wsf);

    table_kernel<<<(TBL + 63) / 64, 64, 0, stream>>>(
        wsf, ln_g, ln_b, W2, b2, Wr, br, table);

    gather_kernel<<<(B / 4 + 255) / 256, 256, 0, stream>>>(
        (const ivec4*)x, table, (fvec4*)d_out, B / 4);
}